// Round 3
// baseline (263.254 us; speedup 1.0000x reference)
//
#include <hip/hip_runtime.h>

#define MASK_VALF 1000000000000.0f

typedef __attribute__((ext_vector_type(8))) short s16x8;   // 8 bf16 (4 VGPRs)
typedef __attribute__((ext_vector_type(4))) float f32x4;   // MFMA acc

__device__ __forceinline__ unsigned f2bf_u(float f) {
    union { float f; unsigned u; } v; v.f = f;
    return (v.u + 0x7FFFu + ((v.u >> 16) & 1u)) >> 16;  // RNE, low 16 bits valid
}
__device__ __forceinline__ short f2bf(float f) { return (short)(f2bf_u(f) & 0xFFFFu); }

// async global->LDS, 16B per lane; lds pointer must be wave-uniform base.
#define GLOAD16(gp, lp) __builtin_amdgcn_global_load_lds( \
    (const __attribute__((address_space(1))) void*)(gp),  \
    (__attribute__((address_space(3))) void*)(lp), 16, 0, 0)

// ---------------- prep: W transpose->bf16 | sincos table ----------------
// (enc->bf16 pass removed: gemm1 now stages enc f32 directly and converts inline,
//  saving the 63 MB encb round-trip.)
__global__ __launch_bounds__(256) void prep_all(
    const float* __restrict__ W, short* __restrict__ wtb,
    float* __restrict__ scf)
{
    const int blk = blockIdx.x;
    const int t = threadIdx.x;
    if (blk < 864) {
        // W (768 x 1152) f32 -> Wt (1152 x 768) bf16, 32x32 tiles, 256 threads
        __shared__ float tile[32][33];
        int tbx = blk % 36;       // n tile
        int tby = blk / 36;       // k tile
        int tx = t & 31, ty = t >> 5;
#pragma unroll
        for (int r = 0; r < 4; ++r) {
            int row = ty + r * 8;  // k within tile
            tile[row][tx] = W[(tby * 32 + row) * 1152 + tbx * 32 + tx];
        }
        __syncthreads();
#pragma unroll
        for (int r = 0; r < 4; ++r) {
            int row = ty + r * 8;  // n within tile
            wtb[(size_t)(tbx * 32 + row) * 768 + tby * 32 + tx] = f2bf(tile[tx][row]);
        }
    } else {
        // sincos table: [512 pos][32 j] of (cos, sin) pairs
        int id = (blk - 864) * 256 + t;   // 0..16383
        int pos = id >> 5, j = id & 31;
        float inv = powf(10000.0f, -2.0f * (float)j / 64.0f);
        float ang = (float)pos * inv;
        float s, c;
        sincosf(ang, &s, &c);
        scf[id * 2]     = c;
        scf[id * 2 + 1] = s;
    }
}

// ---------------- GEMM1 v3: enc staged as f32 (fused convert) + double-buffer + XCD swizzle ----
// A-tile (enc) staged f32 via global_load_lds (16 KB/buf), converted to bf16 with the SAME
// RNE f2bf during fragment assembly -> numerics identical to the old prep path, but the
// 63 MB enc->encb pass disappears. B-tile (Wt) stays bf16 from prep.
// qk layout: [bh=144][qk=2][s=512][d=64]
__global__ __launch_bounds__(256) void gemm1_rope(
    const float* __restrict__ enc,  // 8192x768 f32 row-major
    const short* __restrict__ Bt,   // 1152x768 bf16 row-major (W^T)
    const float* __restrict__ bias, // 1152
    const float* __restrict__ scf,  // 512 x 64 floats (c,s interleaved)
    short* __restrict__ qk)
{
    __shared__ __align__(16) float As[2][128 * 32];   // 2 x 16 KB
    __shared__ __align__(16) short Bs[2][128 * 32];   // 2 x  8 KB
    const int t = threadIdx.x;
    const int w = t >> 6, lane = t & 63;
    const int lr = lane & 15, quad = lane >> 4;
    const int wm = w >> 1, wn = w & 1;   // wm: n-side 64-range, wn: m-side 64-range

    // bijective XCD swizzle (576 % 8 == 0): XCD lin%8 gets 8 consecutive m-panels x all 9 n-tiles
    const int lin = blockIdx.y * 9 + blockIdx.x;
    const int swz = (lin & 7) * 72 + (lin >> 3);
    const int n0 = (swz % 9) * 128;      // cols (tag*128 + qk*64 + dd)
    const int m0 = (swz / 9) * 128;      // rows of enc (pos dim)

    f32x4 acc[4][4] = {};

    // A (f32): wave w stages rows m0+w*32 .. +31; lane l -> row +(l>>3), col (l&7)*4 f32 (16B)
    const float* gA = enc + (size_t)(m0 + w * 32 + (lane >> 3)) * 768 + (lane & 7) * 4;
    // B (bf16): as before
    const short* gB = Bt + (size_t)(n0 + (t >> 2)) * 768 + (t & 3) * 8;

    // prologue: stage tile 0 into buffer 0
#pragma unroll
    for (int p = 0; p < 4; ++p)
        GLOAD16(gA + (size_t)p * 8 * 768, &As[0][(w * 32 + p * 8) * 32]);
    GLOAD16(gB,            &Bs[0][w * 512]);
    GLOAD16(gB + 64 * 768, &Bs[0][2048 + w * 512]);
    gA += 32; gB += 32;
    __syncthreads();

    for (int kt = 0; kt < 24; ++kt) {
        const int cur = kt & 1, nxt = cur ^ 1;
        if (kt < 23) {
            // issue next tile's stage; completes under this tile's ds_read+cvt+MFMA
#pragma unroll
            for (int p = 0; p < 4; ++p)
                GLOAD16(gA + (size_t)p * 8 * 768, &As[nxt][(w * 32 + p * 8) * 32]);
            GLOAD16(gB,            &Bs[nxt][w * 512]);
            GLOAD16(gB + 64 * 768, &Bs[nxt][2048 + w * 512]);
            gA += 32; gB += 32;
        }
        s16x8 af[4], bw[4];
#pragma unroll
        for (int i = 0; i < 4; ++i)   // A-operand = Wt rows (n dim), bf16 in LDS
            af[i] = *(const s16x8*)&Bs[cur][(wm * 64 + i * 16 + lr) * 32 + quad * 8];
#pragma unroll
        for (int j = 0; j < 4; ++j) { // B-operand = enc rows (m dim), f32 in LDS -> cvt
            const float* fr = &As[cur][(wn * 64 + j * 16 + lr) * 32 + quad * 8];
            const f32x4 lo = *(const f32x4*)&fr[0];
            const f32x4 hi = *(const f32x4*)&fr[4];
            s16x8 b;
            b[0] = f2bf(lo[0]); b[1] = f2bf(lo[1]); b[2] = f2bf(lo[2]); b[3] = f2bf(lo[3]);
            b[4] = f2bf(hi[0]); b[5] = f2bf(hi[1]); b[6] = f2bf(hi[2]); b[7] = f2bf(hi[3]);
            bw[j] = b;
        }
#pragma unroll
        for (int i = 0; i < 4; ++i)
#pragma unroll
            for (int j = 0; j < 4; ++j)
                acc[i][j] = __builtin_amdgcn_mfma_f32_16x16x32_bf16(af[i], bw[j], acc[i][j], 0, 0, 0);
        __syncthreads();
    }

    // epilogue: acc[i][j][r] = D[n = n0+wm*64+i*16+quad*4+r][m = m0+wn*64+j*16+lr]
#pragma unroll
    for (int i = 0; i < 4; ++i) {
        const int colg0 = n0 + wm * 64 + i * 16 + quad * 4;   // 4-aligned
        const float4 bv = *(const float4*)&bias[colg0];
        const int tag = colg0 >> 7;
        const int qkf = (colg0 >> 6) & 1;
        const int dd0 = colg0 & 63;
        const int jj0 = dd0 >> 1;                              // even
        short* qbase = qk + ((size_t)tag * 2 + qkf) * 512 * 64 + dd0;
#pragma unroll
        for (int j = 0; j < 4; ++j) {
            const int rowg = m0 + wn * 64 + j * 16 + lr;
            const int bidx = rowg >> 9;
            const int pos  = rowg & 511;
            const float4 cs = *(const float4*)&scf[pos * 64 + jj0 * 2]; // {c0,s0,c1,s1}
            float x0 = acc[i][j][0] + bv.x;
            float x1 = acc[i][j][1] + bv.y;
            float x2 = acc[i][j][2] + bv.z;
            float x3 = acc[i][j][3] + bv.w;
            float o0 = x0 * cs.x - x1 * cs.y;
            float o1 = x1 * cs.x + x0 * cs.y;
            float o2 = x2 * cs.z - x3 * cs.w;
            float o3 = x3 * cs.z + x2 * cs.w;
            int2 st;
            st.x = (int)(f2bf_u(o0) & 0xFFFFu) | (int)(f2bf_u(o1) << 16);
            st.y = (int)(f2bf_u(o2) & 0xFFFFu) | (int)(f2bf_u(o3) << 16);
            *(int2*)&qbase[((size_t)bidx * 9 * 2 * 512 + pos) * 64] = st;
        }
    }
}

// ---------------- GEMM2: LDS-free. per (b,h): K(512x64) x Q(512x64)^T -> logits^T tile ----------------
// Direct global fragment loads (L2/L3-resident), no LDS/barriers. Plain stores (R0-best;
// nontemporal hint reverted -- it coincided with a +5us drift in R1/R2).
__global__ __launch_bounds__(256) void gemm2_mask(
    const short* __restrict__ qk,
    const int* __restrict__ amask,   // (16,512) int32
    float* __restrict__ out)         // (16,9,512,512) f32
{
    const int t = threadIdx.x;
    const int w = t >> 6, lane = t & 63;
    const int lr = lane & 15, quad = lane >> 4;
    const int wm = w >> 1, wn = w & 1;   // wm: t-side, wn: s-side
    const int bh = blockIdx.z;
    const int bidx = bh / 9;
    const int s0 = blockIdx.y * 128;
    const int t0 = blockIdx.x * 128;

    const short* qbase = qk + (size_t)bh * 2 * 512 * 64;
    const short* kbase = qbase + 512 * 64;

    // per-lane fragment base pointers: row stride 128B, quad*16B column
    const short* kf = kbase + (size_t)(t0 + wm * 64 + lr) * 64 + quad * 8;
    const short* qf = qbase + (size_t)(s0 + wn * 64 + lr) * 64 + quad * 8;

    f32x4 acc[4][4] = {};
#pragma unroll
    for (int kk = 0; kk < 64; kk += 32) {
        s16x8 af[4], bw[4];
#pragma unroll
        for (int i = 0; i < 4; ++i)   // A-operand = K rows (t dim)
            af[i] = *(const s16x8*)&kf[i * 16 * 64 + kk];
#pragma unroll
        for (int j = 0; j < 4; ++j)   // B-operand = Q rows (s dim)
            bw[j] = *(const s16x8*)&qf[j * 16 * 64 + kk];
#pragma unroll
        for (int i = 0; i < 4; ++i)
#pragma unroll
            for (int j = 0; j < 4; ++j)
                acc[i][j] = __builtin_amdgcn_mfma_f32_16x16x32_bf16(af[i], bw[j], acc[i][j], 0, 0, 0);
    }

    // acc[i][j][r] = logits[s = s0+wn*64+j*16+lr][t = t0+wm*64+i*16+quad*4+r]
#pragma unroll
    for (int i = 0; i < 4; ++i) {
        const int tg0 = t0 + wm * 64 + i * 16 + quad * 4;   // 4-aligned
        const int4 am = *(const int4*)&amask[bidx * 512 + tg0];
        const float4 pad = make_float4((float)am.x, (float)am.y, (float)am.z, (float)am.w);
        const float4 mk = make_float4((1.0f - pad.x) * MASK_VALF, (1.0f - pad.y) * MASK_VALF,
                                      (1.0f - pad.z) * MASK_VALF, (1.0f - pad.w) * MASK_VALF);
#pragma unroll
        for (int j = 0; j < 4; ++j) {
            const int sg = s0 + wn * 64 + j * 16 + lr;
            float4 v;
            v.x = (acc[i][j][0] * pad.x - mk.x - (sg > tg0     ? MASK_VALF : 0.0f)) * 0.125f;
            v.y = (acc[i][j][1] * pad.y - mk.y - (sg > tg0 + 1 ? MASK_VALF : 0.0f)) * 0.125f;
            v.z = (acc[i][j][2] * pad.z - mk.z - (sg > tg0 + 2 ? MASK_VALF : 0.0f)) * 0.125f;
            v.w = (acc[i][j][3] * pad.w - mk.w - (sg > tg0 + 3 ? MASK_VALF : 0.0f)) * 0.125f;
            *(float4*)&out[((size_t)bh * 512 + sg) * 512 + tg0] = v;
        }
    }
}

extern "C" void kernel_launch(void* const* d_in, const int* in_sizes, int n_in,
                              void* d_out, int out_size, void* d_ws, size_t ws_size,
                              hipStream_t stream) {
    const float* enc   = (const float*)d_in[0];
    // d_in[1] = token_ids (unused by reference)
    const int*   amask = (const int*)d_in[2];
    const float* W     = (const float*)d_in[3];
    const float* bias  = (const float*)d_in[4];
    float* out = (float*)d_out;

    char* ws = (char*)d_ws;
    short* wtb  = (short*)(ws);                 // 1152*768*2   = 1,769,472 B
    float* scf  = (float*)(ws + 1769472);       // 512*32*8     =   131,072 B
    short* qk   = (short*)(ws + 1900544);       // 144*2*512*64*2 = 18,874,368 B

    prep_all  <<<928, 256, 0, stream>>>(W, wtb, scf);
    gemm1_rope<<<dim3(9, 64), 256, 0, stream>>>(enc, wtb, bias, scf, qk);
    gemm2_mask<<<dim3(4, 4, 144), 256, 0, stream>>>(qk, amask, out);
}

// Round 4
// 226.672 us; speedup vs baseline: 1.1614x; 1.1614x over previous
//
#include <hip/hip_runtime.h>

#define MASK_VALF 1000000000000.0f

typedef __attribute__((ext_vector_type(8))) short s16x8;   // 8 bf16 (4 VGPRs)
typedef __attribute__((ext_vector_type(4))) float f32x4;   // MFMA acc

__device__ __forceinline__ unsigned f2bf_u(float f) {
    union { float f; unsigned u; } v; v.f = f;
    return (v.u + 0x7FFFu + ((v.u >> 16) & 1u)) >> 16;  // RNE, low 16 bits valid
}
__device__ __forceinline__ short f2bf(float f) { return (short)(f2bf_u(f) & 0xFFFFu); }

// async global->LDS, 16B per lane; lds pointer must be wave-uniform base.
#define GLOAD16(gp, lp) __builtin_amdgcn_global_load_lds( \
    (const __attribute__((address_space(1))) void*)(gp),  \
    (__attribute__((address_space(3))) void*)(lp), 16, 0, 0)

// ---------------- fused prep: enc->bf16 | W transpose->bf16 | sincos table ----------------
__global__ __launch_bounds__(256) void prep_all(
    const float* __restrict__ enc, short* __restrict__ encb,
    const float* __restrict__ W, short* __restrict__ wtb,
    float* __restrict__ scf)
{
    const int blk = blockIdx.x;
    const int t = threadIdx.x;
    if (blk < 6144) {
        // enc f32 -> bf16, 4 elements/thread
        int i = blk * 256 + t;
        float4 v = ((const float4*)enc)[i];
        short4 o;
        o.x = f2bf(v.x); o.y = f2bf(v.y); o.z = f2bf(v.z); o.w = f2bf(v.w);
        ((short4*)encb)[i] = o;
    } else if (blk < 7008) {
        // W (768 x 1152) f32 -> Wt (1152 x 768) bf16, 32x32 tiles, 256 threads
        __shared__ float tile[32][33];
        int tb = blk - 6144;
        int tbx = tb % 36;       // n tile
        int tby = tb / 36;       // k tile
        int tx = t & 31, ty = t >> 5;
#pragma unroll
        for (int r = 0; r < 4; ++r) {
            int row = ty + r * 8;  // k within tile
            tile[row][tx] = W[(tby * 32 + row) * 1152 + tbx * 32 + tx];
        }
        __syncthreads();
#pragma unroll
        for (int r = 0; r < 4; ++r) {
            int row = ty + r * 8;  // n within tile
            wtb[(size_t)(tbx * 32 + row) * 768 + tby * 32 + tx] = f2bf(tile[tx][row]);
        }
    } else {
        // sincos table: [512 pos][32 j] of (cos, sin) pairs
        int id = (blk - 7008) * 256 + t;   // 0..16383
        int pos = id >> 5, j = id & 31;
        float inv = powf(10000.0f, -2.0f * (float)j / 64.0f);
        float ang = (float)pos * inv;
        float s, c;
        sincosf(ang, &s, &c);
        scf[id * 2]     = c;
        scf[id * 2 + 1] = s;
    }
}

// ---------------- GEMM1 v4: bf16 dbuf + XCD swizzle + BOTH-SIDES chunk swizzle ----------------
// R3 counters: gemm1 is LDS-conflict-bound (6.19M SQ_LDS_BANK_CONFLICT, MfmaUtil 6%).
// Linear [128][32]-short tiles have bank base (row*16+quad*4)%32 = 16*(row&1)+4*quad:
// only 2 values across the 16 lr-lanes of a quad -> 8-way ds_read_b128 conflict (2.94x).
// Fix per rule #21 (global_load_lds writes linearly, can't swizzle the dest): pre-swizzle
// the GLOBAL source chunk and apply the same XOR on the read:
//   store: row r's 16B chunk c lands at slot c ^ ((r>>1)&3)   (permute per-lane global addr)
//   read : want K-chunk quad -> read slot quad ^ ((lr>>1)&3)  (base rows are 16-aligned)
// Bank base becomes 16*(lr&1)+4*(quad^((lr>>1)&3)): 8 distinct slots / 16 lanes = 2-way (free).
// Coalescing unchanged (permutation stays within each row's 64B). Same swizzle valid for the
// +64-row half ((r+64)>>1 & 3 == (r>>1)&3).
// XCD swizzle (576=8x72): fetch is compulsory-only (R3: 26.6MB). qk: [bh=144][qk=2][s=512][d=64]
__global__ __launch_bounds__(256) void gemm1_rope(
    const short* __restrict__ A,    // 8192x768 bf16 row-major (enc)
    const short* __restrict__ Bt,   // 1152x768 bf16 row-major (W^T)
    const float* __restrict__ bias, // 1152
    const float* __restrict__ scf,  // 512 x 64 floats (c,s interleaved)
    short* __restrict__ qk)
{
    __shared__ __align__(16) short As[2][128 * 32];
    __shared__ __align__(16) short Bs[2][128 * 32];
    const int t = threadIdx.x;
    const int w = t >> 6, lane = t & 63;
    const int lr = lane & 15, quad = lane >> 4;
    const int wm = w >> 1, wn = w & 1;   // wm: n-side 64-range, wn: m-side 64-range

    // bijective XCD swizzle: XCD lin%8 gets 8 consecutive m-panels x all 9 n-tiles
    const int lin = blockIdx.y * 9 + blockIdx.x;
    const int swz = (lin & 7) * 72 + (lin >> 3);
    const int n0 = (swz % 9) * 128;      // cols (tag*128 + qk*64 + dd)
    const int m0 = (swz / 9) * 128;      // rows of enc (pos dim)

    f32x4 acc[4][4] = {};

    // staging: lane covers row srow = t>>2 (0..63) and srow+64; source chunk pre-swizzled
    const int srow = t >> 2;
    const int sch  = ((t & 3) ^ ((srow >> 1) & 3)) * 8;
    const short* gA = A  + (size_t)(m0 + srow) * 768 + sch;
    const short* gB = Bt + (size_t)(n0 + srow) * 768 + sch;

    // read-side slot: base rows (wm*64+i*16) are 16-aligned -> ((row>>1)&3) == ((lr>>1)&3)
    const int pcs = (quad ^ ((lr >> 1) & 3)) * 8;

    // prologue: stage tile 0 into buffer 0
    GLOAD16(gA,            &As[0][w * 512]);
    GLOAD16(gA + 64 * 768, &As[0][2048 + w * 512]);
    GLOAD16(gB,            &Bs[0][w * 512]);
    GLOAD16(gB + 64 * 768, &Bs[0][2048 + w * 512]);
    gA += 32; gB += 32;
    __syncthreads();

    for (int kt = 0; kt < 24; ++kt) {
        const int cur = kt & 1, nxt = cur ^ 1;
        if (kt < 23) {
            // issue next tile's stage; completes under this tile's ds_read+MFMA
            GLOAD16(gA,            &As[nxt][w * 512]);
            GLOAD16(gA + 64 * 768, &As[nxt][2048 + w * 512]);
            GLOAD16(gB,            &Bs[nxt][w * 512]);
            GLOAD16(gB + 64 * 768, &Bs[nxt][2048 + w * 512]);
            gA += 32; gB += 32;
        }
        s16x8 af[4], bw[4];
#pragma unroll
        for (int i = 0; i < 4; ++i)   // A-operand = Wt rows (n dim)
            af[i] = *(const s16x8*)&Bs[cur][(wm * 64 + i * 16 + lr) * 32 + pcs];
#pragma unroll
        for (int j = 0; j < 4; ++j)   // B-operand = enc rows (m dim)
            bw[j] = *(const s16x8*)&As[cur][(wn * 64 + j * 16 + lr) * 32 + pcs];
#pragma unroll
        for (int i = 0; i < 4; ++i)
#pragma unroll
            for (int j = 0; j < 4; ++j)
                acc[i][j] = __builtin_amdgcn_mfma_f32_16x16x32_bf16(af[i], bw[j], acc[i][j], 0, 0, 0);
        __syncthreads();
    }

    // epilogue: acc[i][j][r] = D[n = n0+wm*64+i*16+quad*4+r][m = m0+wn*64+j*16+lr]
#pragma unroll
    for (int i = 0; i < 4; ++i) {
        const int colg0 = n0 + wm * 64 + i * 16 + quad * 4;   // 4-aligned
        const float4 bv = *(const float4*)&bias[colg0];
        const int tag = colg0 >> 7;
        const int qkf = (colg0 >> 6) & 1;
        const int dd0 = colg0 & 63;
        const int jj0 = dd0 >> 1;                              // even
        short* qbase = qk + ((size_t)tag * 2 + qkf) * 512 * 64 + dd0;
#pragma unroll
        for (int j = 0; j < 4; ++j) {
            const int rowg = m0 + wn * 64 + j * 16 + lr;
            const int bidx = rowg >> 9;
            const int pos  = rowg & 511;
            const float4 cs = *(const float4*)&scf[pos * 64 + jj0 * 2]; // {c0,s0,c1,s1}
            float x0 = acc[i][j][0] + bv.x;
            float x1 = acc[i][j][1] + bv.y;
            float x2 = acc[i][j][2] + bv.z;
            float x3 = acc[i][j][3] + bv.w;
            float o0 = x0 * cs.x - x1 * cs.y;
            float o1 = x1 * cs.x + x0 * cs.y;
            float o2 = x2 * cs.z - x3 * cs.w;
            float o3 = x3 * cs.z + x2 * cs.w;
            int2 st;
            st.x = (int)(f2bf_u(o0) & 0xFFFFu) | (int)(f2bf_u(o1) << 16);
            st.y = (int)(f2bf_u(o2) & 0xFFFFu) | (int)(f2bf_u(o3) << 16);
            *(int2*)&qbase[((size_t)bidx * 9 * 2 * 512 + pos) * 64] = st;
        }
    }
}

// ---------------- GEMM2: LDS-free. per (b,h): K(512x64) x Q(512x64)^T -> logits^T tile ----------------
// Direct global fragment loads (L2/L3-resident), no LDS/barriers, plain float4 stores.
// R1 post-mortem: output-write-bound (~30us floor).
__global__ __launch_bounds__(256) void gemm2_mask(
    const short* __restrict__ qk,
    const int* __restrict__ amask,   // (16,512) int32
    float* __restrict__ out)         // (16,9,512,512) f32
{
    const int t = threadIdx.x;
    const int w = t >> 6, lane = t & 63;
    const int lr = lane & 15, quad = lane >> 4;
    const int wm = w >> 1, wn = w & 1;   // wm: t-side, wn: s-side
    const int bh = blockIdx.z;
    const int bidx = bh / 9;
    const int s0 = blockIdx.y * 128;
    const int t0 = blockIdx.x * 128;

    const short* qbase = qk + (size_t)bh * 2 * 512 * 64;
    const short* kbase = qbase + 512 * 64;

    // per-lane fragment base pointers: row stride 128B, quad*16B column
    const short* kf = kbase + (size_t)(t0 + wm * 64 + lr) * 64 + quad * 8;
    const short* qf = qbase + (size_t)(s0 + wn * 64 + lr) * 64 + quad * 8;

    f32x4 acc[4][4] = {};
#pragma unroll
    for (int kk = 0; kk < 64; kk += 32) {
        s16x8 af[4], bw[4];
#pragma unroll
        for (int i = 0; i < 4; ++i)   // A-operand = K rows (t dim)
            af[i] = *(const s16x8*)&kf[i * 16 * 64 + kk];
#pragma unroll
        for (int j = 0; j < 4; ++j)   // B-operand = Q rows (s dim)
            bw[j] = *(const s16x8*)&qf[j * 16 * 64 + kk];
#pragma unroll
        for (int i = 0; i < 4; ++i)
#pragma unroll
            for (int j = 0; j < 4; ++j)
                acc[i][j] = __builtin_amdgcn_mfma_f32_16x16x32_bf16(af[i], bw[j], acc[i][j], 0, 0, 0);
    }

    // acc[i][j][r] = logits[s = s0+wn*64+j*16+lr][t = t0+wm*64+i*16+quad*4+r]
#pragma unroll
    for (int i = 0; i < 4; ++i) {
        const int tg0 = t0 + wm * 64 + i * 16 + quad * 4;   // 4-aligned
        const int4 am = *(const int4*)&amask[bidx * 512 + tg0];
        const float4 pad = make_float4((float)am.x, (float)am.y, (float)am.z, (float)am.w);
        const float4 mk = make_float4((1.0f - pad.x) * MASK_VALF, (1.0f - pad.y) * MASK_VALF,
                                      (1.0f - pad.z) * MASK_VALF, (1.0f - pad.w) * MASK_VALF);
#pragma unroll
        for (int j = 0; j < 4; ++j) {
            const int sg = s0 + wn * 64 + j * 16 + lr;
            float4 v;
            v.x = (acc[i][j][0] * pad.x - mk.x - (sg > tg0     ? MASK_VALF : 0.0f)) * 0.125f;
            v.y = (acc[i][j][1] * pad.y - mk.y - (sg > tg0 + 1 ? MASK_VALF : 0.0f)) * 0.125f;
            v.z = (acc[i][j][2] * pad.z - mk.z - (sg > tg0 + 2 ? MASK_VALF : 0.0f)) * 0.125f;
            v.w = (acc[i][j][3] * pad.w - mk.w - (sg > tg0 + 3 ? MASK_VALF : 0.0f)) * 0.125f;
            *(float4*)&out[((size_t)bh * 512 + sg) * 512 + tg0] = v;
        }
    }
}

extern "C" void kernel_launch(void* const* d_in, const int* in_sizes, int n_in,
                              void* d_out, int out_size, void* d_ws, size_t ws_size,
                              hipStream_t stream) {
    const float* enc   = (const float*)d_in[0];
    // d_in[1] = token_ids (unused by reference)
    const int*   amask = (const int*)d_in[2];
    const float* W     = (const float*)d_in[3];
    const float* bias  = (const float*)d_in[4];
    float* out = (float*)d_out;

    char* ws = (char*)d_ws;
    short* encb = (short*)(ws);                 // 8192*768*2   = 12,582,912 B
    short* wtb  = (short*)(ws + 12582912);      // 1152*768*2   =  1,769,472 B
    float* scf  = (float*)(ws + 14352384);      // 512*32*8     =    131,072 B
    short* qk   = (short*)(ws + 14483456);      // 144*2*512*64*2 = 18,874,368 B

    prep_all  <<<7072, 256, 0, stream>>>(enc, encb, W, wtb, scf);
    gemm1_rope<<<dim3(9, 64), 256, 0, stream>>>(encb, wtb, bias, scf, qk);
    gemm2_mask<<<dim3(4, 4, 144), 256, 0, stream>>>(qk, amask, out);
}